// Round 1
// baseline (366.363 us; speedup 1.0000x reference)
//
#include <hip/hip_runtime.h>

#define NN 50000
#define NE 800000
// layer dims
// L1: IN=128 -> HEADS=8 x HID=16 (=128), L2: 128 -> 1 x 64

// ---------------- CSR build ----------------

__global__ __launch_bounds__(256) void init_counts_k(int* counts) {
    int i = blockIdx.x * 256 + threadIdx.x;
    if (i < NN) counts[i] = 0;
}

__global__ __launch_bounds__(256) void hist_k(const int* __restrict__ dst, int* __restrict__ counts) {
    int e = blockIdx.x * 256 + threadIdx.x;
    if (e < NE) atomicAdd(&counts[dst[e]], 1);
}

// single-block exclusive scan of counts -> offs[NN+1], also copy to cursors
__global__ __launch_bounds__(1024) void scan_k(const int* __restrict__ counts,
                                               int* __restrict__ offs,
                                               int* __restrict__ cursors) {
    __shared__ int wsum[16];
    __shared__ int chunk_total;
    __shared__ int running_sh;
    const int t = threadIdx.x;
    const int lane = t & 63, wid = t >> 6;
    if (t == 0) running_sh = 0;
    __syncthreads();
    for (int base = 0; base < NN; base += 1024) {
        const int i = base + t;
        const int v = (i < NN) ? counts[i] : 0;
        // wave inclusive scan
        int s = v;
        #pragma unroll
        for (int off = 1; off < 64; off <<= 1) {
            int tv = __shfl_up(s, off, 64);
            if (lane >= off) s += tv;
        }
        if (lane == 63) wsum[wid] = s;
        __syncthreads();
        if (wid == 0) {
            int ws = (lane < 16) ? wsum[lane] : 0;
            int ss = ws;
            #pragma unroll
            for (int off = 1; off < 16; off <<= 1) {
                int tv = __shfl_up(ss, off, 64);
                if (lane >= off) ss += tv;
            }
            if (lane < 16) wsum[lane] = ss - ws;   // exclusive wave offset
            if (lane == 15) chunk_total = ss;
        }
        __syncthreads();
        const int excl = (s - v) + wsum[wid] + running_sh;
        if (i < NN) { offs[i] = excl; cursors[i] = excl; }
        __syncthreads();
        if (t == 0) running_sh += chunk_total;
        __syncthreads();
    }
    if (t == 0) offs[NN] = running_sh;
}

__global__ __launch_bounds__(256) void scatter_k(const int* __restrict__ dst,
                                                 int* __restrict__ cursors,
                                                 int* __restrict__ eord) {
    int e = blockIdx.x * 256 + threadIdx.x;
    if (e < NE) {
        int pos = atomicAdd(&cursors[dst[e]], 1);
        eord[pos] = e;
    }
}

// ---------------- Layer 1 projection: h1 = x @ W1, el1/er1 fused ----------------
// block = 64 threads (1 wave), 16 nodes per block. thread owns cols t and t+64.
__global__ __launch_bounds__(64) void proj1_k(const float* __restrict__ x,
                                              const float* __restrict__ W1,
                                              const float* __restrict__ al1,
                                              const float* __restrict__ ar1,
                                              float* __restrict__ h1,
                                              float* __restrict__ el1,
                                              float* __restrict__ er1) {
    __shared__ float xs[16 * 128];
    const int t = threadIdx.x;
    const int n0 = blockIdx.x * 16;
    const float4* xg = (const float4*)(x + (size_t)n0 * 128);
    float4* xs4 = (float4*)xs;
    for (int i = t; i < 512; i += 64) xs4[i] = xg[i];
    __syncthreads();

    float acc0[16], acc1[16];
    #pragma unroll
    for (int nn = 0; nn < 16; nn++) { acc0[nn] = 0.f; acc1[nn] = 0.f; }
    const int j0 = t, j1 = t + 64;
    for (int k = 0; k < 128; k += 4) {
        float wa[4], wb[4];
        #pragma unroll
        for (int q = 0; q < 4; q++) {
            wa[q] = W1[(size_t)(k + q) * 128 + j0];
            wb[q] = W1[(size_t)(k + q) * 128 + j1];
        }
        #pragma unroll
        for (int nn = 0; nn < 16; nn++) {
            const float4 xv = *reinterpret_cast<const float4*>(&xs[nn * 128 + k]);
            acc0[nn] = fmaf(xv.x, wa[0], fmaf(xv.y, wa[1], fmaf(xv.z, wa[2], fmaf(xv.w, wa[3], acc0[nn]))));
            acc1[nn] = fmaf(xv.x, wb[0], fmaf(xv.y, wb[1], fmaf(xv.z, wb[2], fmaf(xv.w, wb[3], acc1[nn]))));
        }
    }
    const int h0 = j0 >> 4, d0 = j0 & 15, h1i = j1 >> 4;
    const float a0 = al1[h0 * 16 + d0], r0 = ar1[h0 * 16 + d0];
    const float a1 = al1[h1i * 16 + d0], r1 = ar1[h1i * 16 + d0];
    #pragma unroll
    for (int nn = 0; nn < 16; nn++) {
        const int n = n0 + nn;
        h1[(size_t)n * 128 + j0] = acc0[nn];
        h1[(size_t)n * 128 + j1] = acc1[nn];
        float pe0 = acc0[nn] * a0, pr0 = acc0[nn] * r0;
        float pe1 = acc1[nn] * a1, pr1 = acc1[nn] * r1;
        #pragma unroll
        for (int m = 1; m < 16; m <<= 1) {
            pe0 += __shfl_xor(pe0, m, 64);
            pr0 += __shfl_xor(pr0, m, 64);
            pe1 += __shfl_xor(pe1, m, 64);
            pr1 += __shfl_xor(pr1, m, 64);
        }
        if (d0 == 0) {
            el1[(size_t)n * 8 + h0] = pe0;
            er1[(size_t)n * 8 + h0] = pr0;
            el1[(size_t)n * 8 + h1i] = pe1;
            er1[(size_t)n * 8 + h1i] = pr1;
        }
    }
}

// ---------------- Layer 1 aggregation (per-dst, online softmax) ----------------
// block = 128 threads per dst node; thread owns output element t (head t>>4, dim t&15)
__global__ __launch_bounds__(128) void agg1_k(const int* __restrict__ offs,
                                              const int* __restrict__ eord,
                                              const int* __restrict__ src,
                                              const float* __restrict__ wE,
                                              const float* __restrict__ h1,
                                              const float* __restrict__ el1,
                                              const float* __restrict__ er1,
                                              const float* __restrict__ b1,
                                              float* __restrict__ h2in) {
    const int n = blockIdx.x;
    const int t = threadIdx.x;
    const int beg = offs[n];
    const int deg = offs[n + 1] - beg;
    __shared__ float le[16 * 8], p[16 * 8], lw[16];
    __shared__ int lsrc[16];
    __shared__ float ersh[8], msh[8], zsh[8], ssh[8];
    if (t < 8) { ersh[t] = er1[(size_t)n * 8 + t]; msh[t] = -1e30f; zsh[t] = 0.f; }
    const int ho = t >> 4;
    const int e8 = t >> 3, h8 = t & 7;
    float acc = 0.f;
    for (int base = 0; base < deg; base += 16) {
        const int tile = min(16, deg - base);
        __syncthreads();
        if (e8 < tile) {
            const int eid = eord[beg + base + e8];
            const int s = src[eid];
            if (h8 == 0) { lsrc[e8] = s; lw[e8] = wE[eid]; }
            float lg = el1[(size_t)s * 8 + h8] + ersh[h8];
            lg = lg > 0.f ? lg : 0.2f * lg;
            le[e8 * 8 + h8] = lg;
        }
        __syncthreads();
        if (t < 8) {
            const float mo = msh[t];
            float tm = mo;
            for (int i = 0; i < tile; i++) tm = fmaxf(tm, le[i * 8 + t]);
            const float sc = __expf(mo - tm);
            msh[t] = tm; ssh[t] = sc; zsh[t] *= sc;
        }
        __syncthreads();
        if (e8 < tile) p[e8 * 8 + h8] = __expf(le[e8 * 8 + h8] - msh[h8]);
        __syncthreads();
        if (t < 8) {
            float zz = 0.f;
            for (int i = 0; i < tile; i++) zz += p[i * 8 + t];
            zsh[t] += zz;
        }
        acc *= ssh[ho];
        for (int i = 0; i < tile; i++)
            acc += p[i * 8 + ho] * lw[i] * h1[(size_t)lsrc[i] * 128 + t];
    }
    __syncthreads();
    float val = (deg > 0) ? acc / zsh[ho] : 0.f;
    val += b1[t];
    val = fmaxf(val, 0.f);
    h2in[(size_t)n * 128 + t] = val;
}

// ---------------- Layer 2 projection: h2 = h2in @ W2, el2/er2 fused ----------------
__global__ __launch_bounds__(64) void proj2_k(const float* __restrict__ x,
                                              const float* __restrict__ W2,
                                              const float* __restrict__ al2,
                                              const float* __restrict__ ar2,
                                              float* __restrict__ h2,
                                              float* __restrict__ el2,
                                              float* __restrict__ er2) {
    __shared__ float xs[16 * 128];
    const int t = threadIdx.x;
    const int n0 = blockIdx.x * 16;
    const float4* xg = (const float4*)(x + (size_t)n0 * 128);
    float4* xs4 = (float4*)xs;
    for (int i = t; i < 512; i += 64) xs4[i] = xg[i];
    __syncthreads();

    float acc[16];
    #pragma unroll
    for (int nn = 0; nn < 16; nn++) acc[nn] = 0.f;
    for (int k = 0; k < 128; k += 4) {
        float wq[4];
        #pragma unroll
        for (int q = 0; q < 4; q++) wq[q] = W2[(size_t)(k + q) * 64 + t];
        #pragma unroll
        for (int nn = 0; nn < 16; nn++) {
            const float4 xv = *reinterpret_cast<const float4*>(&xs[nn * 128 + k]);
            acc[nn] = fmaf(xv.x, wq[0], fmaf(xv.y, wq[1], fmaf(xv.z, wq[2], fmaf(xv.w, wq[3], acc[nn]))));
        }
    }
    const float a2 = al2[t], r2 = ar2[t];
    #pragma unroll
    for (int nn = 0; nn < 16; nn++) {
        const int n = n0 + nn;
        h2[(size_t)n * 64 + t] = acc[nn];
        float pe = acc[nn] * a2, pr = acc[nn] * r2;
        #pragma unroll
        for (int m = 1; m < 64; m <<= 1) {
            pe += __shfl_xor(pe, m, 64);
            pr += __shfl_xor(pr, m, 64);
        }
        if (t == 0) { el2[n] = pe; er2[n] = pr; }
    }
}

// ---------------- Layer 2 aggregation ----------------
__global__ __launch_bounds__(64) void agg2_k(const int* __restrict__ offs,
                                             const int* __restrict__ eord,
                                             const int* __restrict__ src,
                                             const float* __restrict__ wE,
                                             const float* __restrict__ h2,
                                             const float* __restrict__ el2,
                                             const float* __restrict__ er2,
                                             const float* __restrict__ b2,
                                             float* __restrict__ out) {
    const int n = blockIdx.x, t = threadIdx.x;
    const int beg = offs[n], deg = offs[n + 1] - beg;
    __shared__ float p[64], lw[64];
    __shared__ int lsrc[64];
    __shared__ float msh, zsh;
    const float erd = er2[n];
    if (t == 0) { msh = -1e30f; zsh = 0.f; }
    float acc = 0.f;
    __syncthreads();
    for (int base = 0; base < deg; base += 64) {
        const int tile = min(64, deg - base);
        float lg = -1e30f; int s = 0; float ww = 0.f;
        if (t < tile) {
            const int eid = eord[beg + base + t];
            s = src[eid]; ww = wE[eid];
            lg = el2[s] + erd;
            lg = lg > 0.f ? lg : 0.2f * lg;
        }
        float tm = lg;
        #pragma unroll
        for (int m = 1; m < 64; m <<= 1) tm = fmaxf(tm, __shfl_xor(tm, m, 64));
        const float mo = msh;
        const float nm = fmaxf(mo, tm);
        const float sc = __expf(mo - nm);
        const float pv = (t < tile) ? __expf(lg - nm) : 0.f;
        float zz = pv;
        #pragma unroll
        for (int m = 1; m < 64; m <<= 1) zz += __shfl_xor(zz, m, 64);
        __syncthreads();
        if (t == 0) { msh = nm; zsh = zsh * sc + zz; }
        p[t] = pv; lsrc[t] = s; lw[t] = ww;
        __syncthreads();
        acc *= sc;
        for (int i = 0; i < tile; i++)
            acc += p[i] * lw[i] * h2[(size_t)lsrc[i] * 64 + t];
    }
    __syncthreads();
    const float res = (deg > 0) ? acc / zsh : 0.f;
    out[(size_t)n * 64 + t] = res + b2[t];
}

// ---------------- host ----------------

extern "C" void kernel_launch(void* const* d_in, const int* in_sizes, int n_in,
                              void* d_out, int out_size, void* d_ws, size_t ws_size,
                              hipStream_t stream) {
    const float* feat = (const float*)d_in[0];
    const int*   srcv = (const int*)d_in[1];
    const int*   dstv = (const int*)d_in[2];
    const float* wE   = (const float*)d_in[3];
    const float* W1   = (const float*)d_in[4];
    const float* al1  = (const float*)d_in[5];
    const float* ar1  = (const float*)d_in[6];
    const float* b1   = (const float*)d_in[7];
    const float* W2   = (const float*)d_in[8];
    const float* al2  = (const float*)d_in[9];
    const float* ar2  = (const float*)d_in[10];
    const float* b2   = (const float*)d_in[11];
    float* out = (float*)d_out;

    char* ws = (char*)d_ws;
    size_t off = 0;
    auto take = [&](size_t bytes) -> char* {
        char* pp = ws + off;
        off = (off + bytes + 255) & ~(size_t)255;
        return pp;
    };
    float* h1   = (float*)take((size_t)NN * 128 * 4);
    float* h2in = (float*)take((size_t)NN * 128 * 4);
    float* h2   = (float*)take((size_t)NN * 64 * 4);
    float* el1  = (float*)take((size_t)NN * 8 * 4);
    float* er1  = (float*)take((size_t)NN * 8 * 4);
    float* el2  = (float*)take((size_t)NN * 4);
    float* er2  = (float*)take((size_t)NN * 4);
    int* counts = (int*)take((size_t)NN * 4);
    int* offs   = (int*)take((size_t)(NN + 1) * 4);
    int* cursors= (int*)take((size_t)NN * 4);
    int* eord   = (int*)take((size_t)NE * 4);

    init_counts_k<<<(NN + 255) / 256, 256, 0, stream>>>(counts);
    hist_k<<<(NE + 255) / 256, 256, 0, stream>>>(dstv, counts);
    scan_k<<<1, 1024, 0, stream>>>(counts, offs, cursors);
    scatter_k<<<(NE + 255) / 256, 256, 0, stream>>>(dstv, cursors, eord);
    proj1_k<<<NN / 16, 64, 0, stream>>>(feat, W1, al1, ar1, h1, el1, er1);
    agg1_k<<<NN, 128, 0, stream>>>(offs, eord, srcv, wE, h1, el1, er1, b1, h2in);
    proj2_k<<<NN / 16, 64, 0, stream>>>(h2in, W2, al2, ar2, h2, el2, er2);
    agg2_k<<<NN, 64, 0, stream>>>(offs, eord, srcv, wE, h2, el2, er2, b2, out);
}

// Round 2
// 280.089 us; speedup vs baseline: 1.3080x; 1.3080x over previous
//
#include <hip/hip_runtime.h>
#include <hip/hip_fp16.h>

#define NN 50000
#define NE 800000
#define NB_C ((NN + 255) / 256)   // 196 chunks of 256

// ---------------- CSR build ----------------

__global__ __launch_bounds__(256) void init_counts_k(int* counts) {
    int i = blockIdx.x * 256 + threadIdx.x;
    if (i < NN) counts[i] = 0;
}

__global__ __launch_bounds__(256) void hist_k(const int* __restrict__ dst, int* __restrict__ counts) {
    int e = blockIdx.x * 256 + threadIdx.x;
    if (e < NE) atomicAdd(&counts[dst[e]], 1);
}

// per-256-chunk sums
__global__ __launch_bounds__(256) void partial_k(const int* __restrict__ counts, int* __restrict__ bsum) {
    __shared__ int ws[4];
    const int t = threadIdx.x, i = blockIdx.x * 256 + t;
    int s = (i < NN) ? counts[i] : 0;
    #pragma unroll
    for (int m = 1; m < 64; m <<= 1) s += __shfl_xor(s, m, 64);
    if ((t & 63) == 0) ws[t >> 6] = s;
    __syncthreads();
    if (t == 0) bsum[blockIdx.x] = ws[0] + ws[1] + ws[2] + ws[3];
}

// single tiny block: exclusive scan of the 196 chunk sums; writes offs[NN]=total
__global__ __launch_bounds__(256) void scanb_k(const int* __restrict__ bsum,
                                               int* __restrict__ boff,
                                               int* __restrict__ offs_last) {
    __shared__ int wsum[4];
    const int t = threadIdx.x, lane = t & 63, wid = t >> 6;
    const int v = (t < NB_C) ? bsum[t] : 0;
    int s = v;
    #pragma unroll
    for (int off = 1; off < 64; off <<= 1) {
        int tv = __shfl_up(s, off, 64);
        if (lane >= off) s += tv;
    }
    if (lane == 63) wsum[wid] = s;
    __syncthreads();
    int add = 0;
    for (int w = 0; w < wid; w++) add += wsum[w];
    const int excl = s - v + add;
    if (t < NB_C) boff[t] = excl;
    if (t == NB_C - 1) offs_last[0] = excl + v;
}

// chunk-local exclusive scan + chunk offset -> offs, cursors
__global__ __launch_bounds__(256) void offs_k(const int* __restrict__ counts,
                                              const int* __restrict__ boff,
                                              int* __restrict__ offs,
                                              int* __restrict__ cursors) {
    __shared__ int wsum[4];
    const int t = threadIdx.x, lane = t & 63, wid = t >> 6;
    const int i = blockIdx.x * 256 + t;
    const int v = (i < NN) ? counts[i] : 0;
    int s = v;
    #pragma unroll
    for (int off = 1; off < 64; off <<= 1) {
        int tv = __shfl_up(s, off, 64);
        if (lane >= off) s += tv;
    }
    if (lane == 63) wsum[wid] = s;
    __syncthreads();
    int add = boff[blockIdx.x];
    for (int w = 0; w < wid; w++) add += wsum[w];
    const int excl = s - v + add;
    if (i < NN) { offs[i] = excl; cursors[i] = excl; }
}

__global__ __launch_bounds__(256) void scatter_k(const int* __restrict__ dst,
                                                 int* __restrict__ cursors,
                                                 int* __restrict__ eord) {
    int e = blockIdx.x * 256 + threadIdx.x;
    if (e < NE) {
        int pos = atomicAdd(&cursors[dst[e]], 1);
        eord[pos] = e;
    }
}

// ---------------- Layer 1 projection: h1h(fp16) = x @ W1, el1/er1 fused ----------------
__global__ __launch_bounds__(64) void proj1_k(const float* __restrict__ x,
                                              const float* __restrict__ W1,
                                              const float* __restrict__ al1,
                                              const float* __restrict__ ar1,
                                              __half* __restrict__ h1h,
                                              float* __restrict__ el1,
                                              float* __restrict__ er1) {
    __shared__ float xs[16 * 128];
    const int t = threadIdx.x;
    const int n0 = blockIdx.x * 16;
    const float4* xg = (const float4*)(x + (size_t)n0 * 128);
    float4* xs4 = (float4*)xs;
    for (int i = t; i < 512; i += 64) xs4[i] = xg[i];
    __syncthreads();

    float acc0[16], acc1[16];
    #pragma unroll
    for (int nn = 0; nn < 16; nn++) { acc0[nn] = 0.f; acc1[nn] = 0.f; }
    const int j0 = t, j1 = t + 64;
    for (int k = 0; k < 128; k += 4) {
        float wa[4], wb[4];
        #pragma unroll
        for (int q = 0; q < 4; q++) {
            wa[q] = W1[(size_t)(k + q) * 128 + j0];
            wb[q] = W1[(size_t)(k + q) * 128 + j1];
        }
        #pragma unroll
        for (int nn = 0; nn < 16; nn++) {
            const float4 xv = *reinterpret_cast<const float4*>(&xs[nn * 128 + k]);
            acc0[nn] = fmaf(xv.x, wa[0], fmaf(xv.y, wa[1], fmaf(xv.z, wa[2], fmaf(xv.w, wa[3], acc0[nn]))));
            acc1[nn] = fmaf(xv.x, wb[0], fmaf(xv.y, wb[1], fmaf(xv.z, wb[2], fmaf(xv.w, wb[3], acc1[nn]))));
        }
    }
    const int h0 = j0 >> 4, d0 = j0 & 15, h1i = j1 >> 4;
    const float a0 = al1[h0 * 16 + d0], r0 = ar1[h0 * 16 + d0];
    const float a1 = al1[h1i * 16 + d0], r1 = ar1[h1i * 16 + d0];
    #pragma unroll
    for (int nn = 0; nn < 16; nn++) {
        const int n = n0 + nn;
        h1h[(size_t)n * 128 + j0] = __float2half(acc0[nn]);
        h1h[(size_t)n * 128 + j1] = __float2half(acc1[nn]);
        float pe0 = acc0[nn] * a0, pr0 = acc0[nn] * r0;
        float pe1 = acc1[nn] * a1, pr1 = acc1[nn] * r1;
        #pragma unroll
        for (int m = 1; m < 16; m <<= 1) {
            pe0 += __shfl_xor(pe0, m, 64);
            pr0 += __shfl_xor(pr0, m, 64);
            pe1 += __shfl_xor(pe1, m, 64);
            pr1 += __shfl_xor(pr1, m, 64);
        }
        if (d0 == 0) {
            el1[(size_t)n * 8 + h0] = pe0;
            er1[(size_t)n * 8 + h0] = pr0;
            el1[(size_t)n * 8 + h1i] = pe1;
            er1[(size_t)n * 8 + h1i] = pr1;
        }
    }
}

// ---------------- Layer 1 aggregation (per-dst, online softmax, wave-parallel) ----------------
// 128 threads per dst node; thread owns output element t (head t>>4); softmax lanes (e8=t>>3, h8=t&7)
__global__ __launch_bounds__(128) void agg1_k(const int* __restrict__ offs,
                                              const int* __restrict__ eord,
                                              const int* __restrict__ src,
                                              const float* __restrict__ wE,
                                              const __half* __restrict__ h1h,
                                              const float* __restrict__ el1,
                                              const float* __restrict__ er1,
                                              const float* __restrict__ b1,
                                              float* __restrict__ h2in) {
    const int n = blockIdx.x, t = threadIdx.x;
    const int beg = offs[n], deg = offs[n + 1] - beg;
    const int ho = t >> 4;
    const int e8 = t >> 3, h8 = t & 7;
    const int wid = t >> 6;
    __shared__ float pw[16 * 8];
    __shared__ int lsrc[16];
    __shared__ float lwsh[16];
    __shared__ float ersh[8], msh[8], zsh[8], ssh[8];
    __shared__ float wmax[2][8], wz[2][8];
    if (t < 8) { ersh[t] = er1[(size_t)n * 8 + t]; msh[t] = -1e30f; zsh[t] = 0.f; }
    float acc = 0.f;
    for (int base = 0; base < deg; base += 16) {
        const int tile = min(16, deg - base);
        __syncthreads();
        float lg = -1e30f;
        if (e8 < tile) {
            const int eid = eord[beg + base + e8];
            const int s = src[eid];
            if (h8 == 0) { lsrc[e8] = s; lwsh[e8] = wE[eid]; }
            const float v = el1[(size_t)s * 8 + h8] + ersh[h8];
            lg = v > 0.f ? v : 0.2f * v;
        } else if (h8 == 0) { lsrc[e8] = 0; lwsh[e8] = 0.f; }
        float tm = lg;
        tm = fmaxf(tm, __shfl_xor(tm, 8, 64));
        tm = fmaxf(tm, __shfl_xor(tm, 16, 64));
        tm = fmaxf(tm, __shfl_xor(tm, 32, 64));
        if ((t & 56) == 0) wmax[wid][h8] = tm;
        __syncthreads();
        const float m_old = msh[h8];
        const float m_new = fmaxf(m_old, fmaxf(wmax[0][h8], wmax[1][h8]));
        const float p = __expf(lg - m_new);           // 0 for padded lanes
        const float pwv = p * lwsh[e8];
        float zz = p;
        zz += __shfl_xor(zz, 8, 64);
        zz += __shfl_xor(zz, 16, 64);
        zz += __shfl_xor(zz, 32, 64);
        if ((t & 56) == 0) wz[wid][h8] = zz;
        pw[e8 * 8 + h8] = pwv;
        if (t < 8) { const float sc = __expf(m_old - m_new); msh[t] = m_new; ssh[t] = sc; }
        __syncthreads();
        if (t < 8) zsh[t] = zsh[t] * ssh[t] + wz[0][t] + wz[1][t];
        acc *= ssh[ho];
        const __half* hp = h1h + t;
        #pragma unroll
        for (int i = 0; i < 16; i++)
            acc = fmaf(pw[i * 8 + ho], __half2float(hp[(size_t)lsrc[i] * 128]), acc);
    }
    __syncthreads();
    float val = (deg > 0) ? acc / zsh[ho] : 0.f;
    val += b1[t];
    h2in[(size_t)n * 128 + t] = fmaxf(val, 0.f);
}

// ---------------- Layer 2 projection: h2h(fp16) = h2in @ W2, el2/er2 fused ----------------
__global__ __launch_bounds__(64) void proj2_k(const float* __restrict__ x,
                                              const float* __restrict__ W2,
                                              const float* __restrict__ al2,
                                              const float* __restrict__ ar2,
                                              __half* __restrict__ h2h,
                                              float* __restrict__ el2,
                                              float* __restrict__ er2) {
    __shared__ float xs[16 * 128];
    const int t = threadIdx.x;
    const int n0 = blockIdx.x * 16;
    const float4* xg = (const float4*)(x + (size_t)n0 * 128);
    float4* xs4 = (float4*)xs;
    for (int i = t; i < 512; i += 64) xs4[i] = xg[i];
    __syncthreads();

    float acc[16];
    #pragma unroll
    for (int nn = 0; nn < 16; nn++) acc[nn] = 0.f;
    for (int k = 0; k < 128; k += 4) {
        float wq[4];
        #pragma unroll
        for (int q = 0; q < 4; q++) wq[q] = W2[(size_t)(k + q) * 64 + t];
        #pragma unroll
        for (int nn = 0; nn < 16; nn++) {
            const float4 xv = *reinterpret_cast<const float4*>(&xs[nn * 128 + k]);
            acc[nn] = fmaf(xv.x, wq[0], fmaf(xv.y, wq[1], fmaf(xv.z, wq[2], fmaf(xv.w, wq[3], acc[nn]))));
        }
    }
    const float a2 = al2[t], r2 = ar2[t];
    #pragma unroll
    for (int nn = 0; nn < 16; nn++) {
        const int n = n0 + nn;
        h2h[(size_t)n * 64 + t] = __float2half(acc[nn]);
        float pe = acc[nn] * a2, pr = acc[nn] * r2;
        #pragma unroll
        for (int m = 1; m < 64; m <<= 1) {
            pe += __shfl_xor(pe, m, 64);
            pr += __shfl_xor(pr, m, 64);
        }
        if (t == 0) { el2[n] = pe; er2[n] = pr; }
    }
}

// ---------------- Layer 2 aggregation ----------------
__global__ __launch_bounds__(64) void agg2_k(const int* __restrict__ offs,
                                             const int* __restrict__ eord,
                                             const int* __restrict__ src,
                                             const float* __restrict__ wE,
                                             const __half* __restrict__ h2h,
                                             const float* __restrict__ el2,
                                             const float* __restrict__ er2,
                                             const float* __restrict__ b2,
                                             float* __restrict__ out) {
    const int n = blockIdx.x, t = threadIdx.x;
    const int beg = offs[n], deg = offs[n + 1] - beg;
    __shared__ float pw[64];
    __shared__ int lsrc[64];
    const float erd = er2[n];
    float m_run = -1e30f, z_run = 0.f, acc = 0.f;
    for (int base = 0; base < deg; base += 64) {
        const int tile = min(64, deg - base);
        __syncthreads();
        float lg = -1e30f; int s = 0; float ww = 0.f;
        if (t < tile) {
            const int eid = eord[beg + base + t];
            s = src[eid]; ww = wE[eid];
            const float v = el2[s] + erd;
            lg = v > 0.f ? v : 0.2f * v;
        }
        float tm = lg;
        #pragma unroll
        for (int m = 1; m < 64; m <<= 1) tm = fmaxf(tm, __shfl_xor(tm, m, 64));
        const float nm = fmaxf(m_run, tm);
        const float sc = __expf(m_run - nm);
        const float pv = __expf(lg - nm);           // 0 for padded lanes
        float zz = pv;
        #pragma unroll
        for (int m = 1; m < 64; m <<= 1) zz += __shfl_xor(zz, m, 64);
        m_run = nm;
        z_run = z_run * sc + zz;
        lsrc[t] = s; pw[t] = pv * ww;
        __syncthreads();
        acc *= sc;
        const __half* hp = h2h + t;
        const int lim = (tile + 15) & ~15;
        for (int i0 = 0; i0 < lim; i0 += 16) {
            #pragma unroll
            for (int i = 0; i < 16; i++)
                acc = fmaf(pw[i0 + i], __half2float(hp[(size_t)lsrc[i0 + i] * 64]), acc);
        }
    }
    const float res = (deg > 0) ? acc / z_run : 0.f;
    out[(size_t)n * 64 + t] = res + b2[t];
}

// ---------------- host ----------------

extern "C" void kernel_launch(void* const* d_in, const int* in_sizes, int n_in,
                              void* d_out, int out_size, void* d_ws, size_t ws_size,
                              hipStream_t stream) {
    const float* feat = (const float*)d_in[0];
    const int*   srcv = (const int*)d_in[1];
    const int*   dstv = (const int*)d_in[2];
    const float* wE   = (const float*)d_in[3];
    const float* W1   = (const float*)d_in[4];
    const float* al1  = (const float*)d_in[5];
    const float* ar1  = (const float*)d_in[6];
    const float* b1   = (const float*)d_in[7];
    const float* W2   = (const float*)d_in[8];
    const float* al2  = (const float*)d_in[9];
    const float* ar2  = (const float*)d_in[10];
    const float* b2   = (const float*)d_in[11];
    float* out = (float*)d_out;

    char* ws = (char*)d_ws;
    size_t off = 0;
    auto take = [&](size_t bytes) -> char* {
        char* pp = ws + off;
        off = (off + bytes + 255) & ~(size_t)255;
        return pp;
    };
    __half* h1h = (__half*)take((size_t)NN * 128 * 2);
    __half* h2h = (__half*)take((size_t)NN * 64 * 2);
    float* h2in = (float*)take((size_t)NN * 128 * 4);
    float* el1  = (float*)take((size_t)NN * 8 * 4);
    float* er1  = (float*)take((size_t)NN * 8 * 4);
    float* el2  = (float*)take((size_t)NN * 4);
    float* er2  = (float*)take((size_t)NN * 4);
    int* counts = (int*)take((size_t)NN * 4);
    int* offs   = (int*)take((size_t)(NN + 1) * 4);
    int* cursors= (int*)take((size_t)NN * 4);
    int* eord   = (int*)take((size_t)NE * 4);
    int* bsum   = (int*)take((size_t)NB_C * 4);
    int* boff   = (int*)take((size_t)NB_C * 4);

    init_counts_k<<<NB_C, 256, 0, stream>>>(counts);
    hist_k<<<(NE + 255) / 256, 256, 0, stream>>>(dstv, counts);
    partial_k<<<NB_C, 256, 0, stream>>>(counts, bsum);
    scanb_k<<<1, 256, 0, stream>>>(bsum, boff, offs + NN);
    offs_k<<<NB_C, 256, 0, stream>>>(counts, boff, offs, cursors);
    scatter_k<<<(NE + 255) / 256, 256, 0, stream>>>(dstv, cursors, eord);
    proj1_k<<<NN / 16, 64, 0, stream>>>(feat, W1, al1, ar1, h1h, el1, er1);
    agg1_k<<<NN, 128, 0, stream>>>(offs, eord, srcv, wE, h1h, el1, er1, b1, h2in);
    proj2_k<<<NN / 16, 64, 0, stream>>>(h2in, W2, al2, ar2, h2h, el2, er2);
    agg2_k<<<NN, 64, 0, stream>>>(offs, eord, srcv, wE, h2h, el2, er2, b2, out);
}

// Round 3
// 248.055 us; speedup vs baseline: 1.4769x; 1.1291x over previous
//
#include <hip/hip_runtime.h>
#include <hip/hip_fp16.h>

#define NN 50000
#define NE 800000
#define NB_C ((NN + 255) / 256)   // 196 chunks of 256

// ---------------- CSR build ----------------

__global__ __launch_bounds__(256) void init_counts_k(int* counts) {
    int i = blockIdx.x * 256 + threadIdx.x;
    if (i < NN) counts[i] = 0;
}

__global__ __launch_bounds__(256) void hist_k(const int* __restrict__ dst, int* __restrict__ counts) {
    int e = blockIdx.x * 256 + threadIdx.x;
    if (e < NE) atomicAdd(&counts[dst[e]], 1);
}

// per-256-chunk sums
__global__ __launch_bounds__(256) void partial_k(const int* __restrict__ counts, int* __restrict__ bsum) {
    __shared__ int ws[4];
    const int t = threadIdx.x, i = blockIdx.x * 256 + t;
    int s = (i < NN) ? counts[i] : 0;
    #pragma unroll
    for (int m = 1; m < 64; m <<= 1) s += __shfl_xor(s, m, 64);
    if ((t & 63) == 0) ws[t >> 6] = s;
    __syncthreads();
    if (t == 0) bsum[blockIdx.x] = ws[0] + ws[1] + ws[2] + ws[3];
}

// single tiny block: exclusive scan of the 196 chunk sums; writes offs[NN]=total
__global__ __launch_bounds__(256) void scanb_k(const int* __restrict__ bsum,
                                               int* __restrict__ boff,
                                               int* __restrict__ offs_last) {
    __shared__ int wsum[4];
    const int t = threadIdx.x, lane = t & 63, wid = t >> 6;
    const int v = (t < NB_C) ? bsum[t] : 0;
    int s = v;
    #pragma unroll
    for (int off = 1; off < 64; off <<= 1) {
        int tv = __shfl_up(s, off, 64);
        if (lane >= off) s += tv;
    }
    if (lane == 63) wsum[wid] = s;
    __syncthreads();
    int add = 0;
    for (int w = 0; w < wid; w++) add += wsum[w];
    const int excl = s - v + add;
    if (t < NB_C) boff[t] = excl;
    if (t == NB_C - 1) offs_last[0] = excl + v;
}

// chunk-local exclusive scan + chunk offset -> offs, cursors
__global__ __launch_bounds__(256) void offs_k(const int* __restrict__ counts,
                                              const int* __restrict__ boff,
                                              int* __restrict__ offs,
                                              int* __restrict__ cursors) {
    __shared__ int wsum[4];
    const int t = threadIdx.x, lane = t & 63, wid = t >> 6;
    const int i = blockIdx.x * 256 + t;
    const int v = (i < NN) ? counts[i] : 0;
    int s = v;
    #pragma unroll
    for (int off = 1; off < 64; off <<= 1) {
        int tv = __shfl_up(s, off, 64);
        if (lane >= off) s += tv;
    }
    if (lane == 63) wsum[wid] = s;
    __syncthreads();
    int add = boff[blockIdx.x];
    for (int w = 0; w < wid; w++) add += wsum[w];
    const int excl = s - v + add;
    if (i < NN) { offs[i] = excl; cursors[i] = excl; }
}

// scatter edges into dst-sorted CSR payload: csr[pos] = {src, w_bits}
__global__ __launch_bounds__(256) void scatter_k(const int* __restrict__ dst,
                                                 const int* __restrict__ src,
                                                 const float* __restrict__ wE,
                                                 int* __restrict__ cursors,
                                                 int2* __restrict__ csr) {
    int e = blockIdx.x * 256 + threadIdx.x;
    if (e < NE) {
        int pos = atomicAdd(&cursors[dst[e]], 1);
        csr[pos] = make_int2(src[e], __float_as_int(wE[e]));
    }
}

// ---------------- Layer 1 projection: h1h(fp16) = x @ W1, el1/er1 fused ----------------
__global__ __launch_bounds__(64) void proj1_k(const float* __restrict__ x,
                                              const float* __restrict__ W1,
                                              const float* __restrict__ al1,
                                              const float* __restrict__ ar1,
                                              __half* __restrict__ h1h,
                                              float* __restrict__ el1,
                                              float* __restrict__ er1) {
    __shared__ float xs[16 * 128];
    const int t = threadIdx.x;
    const int n0 = blockIdx.x * 16;
    const float4* xg = (const float4*)(x + (size_t)n0 * 128);
    float4* xs4 = (float4*)xs;
    for (int i = t; i < 512; i += 64) xs4[i] = xg[i];
    __syncthreads();

    float acc0[16], acc1[16];
    #pragma unroll
    for (int nn = 0; nn < 16; nn++) { acc0[nn] = 0.f; acc1[nn] = 0.f; }
    const int j0 = t, j1 = t + 64;
    for (int k = 0; k < 128; k += 4) {
        float wa[4], wb[4];
        #pragma unroll
        for (int q = 0; q < 4; q++) {
            wa[q] = W1[(size_t)(k + q) * 128 + j0];
            wb[q] = W1[(size_t)(k + q) * 128 + j1];
        }
        #pragma unroll
        for (int nn = 0; nn < 16; nn++) {
            const float4 xv = *reinterpret_cast<const float4*>(&xs[nn * 128 + k]);
            acc0[nn] = fmaf(xv.x, wa[0], fmaf(xv.y, wa[1], fmaf(xv.z, wa[2], fmaf(xv.w, wa[3], acc0[nn]))));
            acc1[nn] = fmaf(xv.x, wb[0], fmaf(xv.y, wb[1], fmaf(xv.z, wb[2], fmaf(xv.w, wb[3], acc1[nn]))));
        }
    }
    const int h0 = j0 >> 4, d0 = j0 & 15, h1i = j1 >> 4;
    const float a0 = al1[h0 * 16 + d0], r0 = ar1[h0 * 16 + d0];
    const float a1 = al1[h1i * 16 + d0], r1 = ar1[h1i * 16 + d0];
    #pragma unroll
    for (int nn = 0; nn < 16; nn++) {
        const int n = n0 + nn;
        h1h[(size_t)n * 128 + j0] = __float2half(acc0[nn]);
        h1h[(size_t)n * 128 + j1] = __float2half(acc1[nn]);
        float pe0 = acc0[nn] * a0, pr0 = acc0[nn] * r0;
        float pe1 = acc1[nn] * a1, pr1 = acc1[nn] * r1;
        #pragma unroll
        for (int m = 1; m < 16; m <<= 1) {
            pe0 += __shfl_xor(pe0, m, 64);
            pr0 += __shfl_xor(pr0, m, 64);
            pe1 += __shfl_xor(pe1, m, 64);
            pr1 += __shfl_xor(pr1, m, 64);
        }
        if (d0 == 0) {
            el1[(size_t)n * 8 + h0] = pe0;
            er1[(size_t)n * 8 + h0] = pr0;
            el1[(size_t)n * 8 + h1i] = pe1;
            er1[(size_t)n * 8 + h1i] = pr1;
        }
    }
}

// ---------------- Layer 1 aggregation: one wave per dst node ----------------
// 128-thread block = 2 independent waves (2 nodes). No __syncthreads (deg differs).
// Lane roles: softmax: head h=l&7, edges e0=l>>3, e1=e0+8 (covers 16-edge tile).
//             values:  dim-group g=l&15 (dims 8g..8g+7, head g>>1), edge subset es=l>>4.
__global__ __launch_bounds__(128) void agg1_k(const int* __restrict__ offs,
                                              const int2* __restrict__ csr,
                                              const __half* __restrict__ h1h,
                                              const float* __restrict__ el1,
                                              const float* __restrict__ er1,
                                              const float* __restrict__ b1,
                                              float* __restrict__ h2in) {
    const int t = threadIdx.x, w = t >> 6, l = t & 63;
    const int n = blockIdx.x * 2 + w;
    const int beg = offs[n], deg = offs[n + 1] - beg;
    __shared__ int   lsrc[2][16];
    __shared__ float lw[2][16];
    __shared__ float pw[2][128];
    const int h = l & 7, g = l & 15, es = l >> 4, hg = g >> 1;
    const int e0 = l >> 3, e1 = e0 + 8;
    const float er_h = er1[(size_t)n * 8 + h];
    float m_run = -1e30f, z_run = 0.f;
    float acc[8];
    #pragma unroll
    for (int j = 0; j < 8; j++) acc[j] = 0.f;
    const float4* hp4 = (const float4*)h1h;

    for (int base = 0; base < deg; base += 16) {
        if (l < 16) {
            int2 pr = (base + l < deg) ? csr[beg + base + l] : make_int2(0, 0);
            lsrc[w][l] = pr.x;
            lw[w][l] = __int_as_float(pr.y);
        }
        asm volatile("" ::: "memory");
        // logits for edges e0, e1 (head h)
        float lg0 = -1e30f, lg1 = -1e30f;
        if (base + e0 < deg) {
            const float v = el1[(size_t)lsrc[w][e0] * 8 + h] + er_h;
            lg0 = v > 0.f ? v : 0.2f * v;
        }
        if (base + e1 < deg) {
            const float v = el1[(size_t)lsrc[w][e1] * 8 + h] + er_h;
            lg1 = v > 0.f ? v : 0.2f * v;
        }
        float tm = fmaxf(lg0, lg1);
        tm = fmaxf(tm, __shfl_xor(tm, 8, 64));
        tm = fmaxf(tm, __shfl_xor(tm, 16, 64));
        tm = fmaxf(tm, __shfl_xor(tm, 32, 64));
        const float m_new = fmaxf(m_run, tm);
        const float sc = __expf(m_run - m_new);
        const float p0 = __expf(lg0 - m_new);
        const float p1 = __expf(lg1 - m_new);
        float za = p0 + p1;
        za += __shfl_xor(za, 8, 64);
        za += __shfl_xor(za, 16, 64);
        za += __shfl_xor(za, 32, 64);
        z_run = z_run * sc + za;
        m_run = m_new;
        pw[w][l] = p0 * lw[w][e0];        // addr e0*8+h == l
        pw[w][l + 64] = p1 * lw[w][e1];   // addr e1*8+h == l+64
        asm volatile("" ::: "memory");
        // rescale + accumulate values
        const float scg = __shfl(sc, hg, 8);
        #pragma unroll
        for (int j = 0; j < 8; j++) acc[j] *= scg;
        const int sA = lsrc[w][es], sB = lsrc[w][es + 4], sC = lsrc[w][es + 8], sD = lsrc[w][es + 12];
        const float pA = pw[w][es * 8 + hg], pB = pw[w][(es + 4) * 8 + hg];
        const float pC = pw[w][(es + 8) * 8 + hg], pD = pw[w][(es + 12) * 8 + hg];
        const float4 vA = hp4[(size_t)sA * 16 + g];
        const float4 vB = hp4[(size_t)sB * 16 + g];
        const float4 vC = hp4[(size_t)sC * 16 + g];
        const float4 vD = hp4[(size_t)sD * 16 + g];
        #pragma unroll
        for (int q = 0; q < 4; q++) {
            const __half2 hA = ((const __half2*)&vA)[q];
            const __half2 hB = ((const __half2*)&vB)[q];
            const __half2 hC = ((const __half2*)&vC)[q];
            const __half2 hD = ((const __half2*)&vD)[q];
            const float2 fA = __half22float2(hA), fB = __half22float2(hB);
            const float2 fC = __half22float2(hC), fD = __half22float2(hD);
            acc[2 * q]     = fmaf(pA, fA.x, fmaf(pB, fB.x, fmaf(pC, fC.x, fmaf(pD, fD.x, acc[2 * q]))));
            acc[2 * q + 1] = fmaf(pA, fA.y, fmaf(pB, fB.y, fmaf(pC, fC.y, fmaf(pD, fD.y, acc[2 * q + 1]))));
        }
        asm volatile("" ::: "memory");
    }
    // reduce partial sums over edge subsets (es: bits 4,5 of l)
    #pragma unroll
    for (int j = 0; j < 8; j++) {
        acc[j] += __shfl_xor(acc[j], 16, 64);
        acc[j] += __shfl_xor(acc[j], 32, 64);
    }
    const float zg = __shfl(z_run, hg, 8);
    if (l < 16) {
        const float inv = (deg > 0) ? 1.f / zg : 0.f;
        const float4* b4 = (const float4*)b1;
        const float4 bb0 = b4[g * 2], bb1 = b4[g * 2 + 1];
        float4 o0, o1;
        o0.x = fmaxf(acc[0] * inv + bb0.x, 0.f);
        o0.y = fmaxf(acc[1] * inv + bb0.y, 0.f);
        o0.z = fmaxf(acc[2] * inv + bb0.z, 0.f);
        o0.w = fmaxf(acc[3] * inv + bb0.w, 0.f);
        o1.x = fmaxf(acc[4] * inv + bb1.x, 0.f);
        o1.y = fmaxf(acc[5] * inv + bb1.y, 0.f);
        o1.z = fmaxf(acc[6] * inv + bb1.z, 0.f);
        o1.w = fmaxf(acc[7] * inv + bb1.w, 0.f);
        float4* op = (float4*)(h2in + (size_t)n * 128 + g * 8);
        op[0] = o0; op[1] = o1;
    }
}

// ---------------- Layer 2 projection: h2h(fp16) = h2in @ W2, el2/er2 fused ----------------
__global__ __launch_bounds__(64) void proj2_k(const float* __restrict__ x,
                                              const float* __restrict__ W2,
                                              const float* __restrict__ al2,
                                              const float* __restrict__ ar2,
                                              __half* __restrict__ h2h,
                                              float* __restrict__ el2,
                                              float* __restrict__ er2) {
    __shared__ float xs[16 * 128];
    const int t = threadIdx.x;
    const int n0 = blockIdx.x * 16;
    const float4* xg = (const float4*)(x + (size_t)n0 * 128);
    float4* xs4 = (float4*)xs;
    for (int i = t; i < 512; i += 64) xs4[i] = xg[i];
    __syncthreads();

    float acc[16];
    #pragma unroll
    for (int nn = 0; nn < 16; nn++) acc[nn] = 0.f;
    for (int k = 0; k < 128; k += 4) {
        float wq[4];
        #pragma unroll
        for (int q = 0; q < 4; q++) wq[q] = W2[(size_t)(k + q) * 64 + t];
        #pragma unroll
        for (int nn = 0; nn < 16; nn++) {
            const float4 xv = *reinterpret_cast<const float4*>(&xs[nn * 128 + k]);
            acc[nn] = fmaf(xv.x, wq[0], fmaf(xv.y, wq[1], fmaf(xv.z, wq[2], fmaf(xv.w, wq[3], acc[nn]))));
        }
    }
    const float a2 = al2[t], r2 = ar2[t];
    #pragma unroll
    for (int nn = 0; nn < 16; nn++) {
        const int n = n0 + nn;
        h2h[(size_t)n * 64 + t] = __float2half(acc[nn]);
        float pe = acc[nn] * a2, pr = acc[nn] * r2;
        #pragma unroll
        for (int m = 1; m < 64; m <<= 1) {
            pe += __shfl_xor(pe, m, 64);
            pr += __shfl_xor(pr, m, 64);
        }
        if (t == 0) { el2[n] = pe; er2[n] = pr; }
    }
}

// ---------------- Layer 2 aggregation: one wave per dst node ----------------
// Lane roles: softmax: edge e=l&15 (4x redundant). values: g=l&7 (dims 8g), es=l>>3.
__global__ __launch_bounds__(128) void agg2_k(const int* __restrict__ offs,
                                              const int2* __restrict__ csr,
                                              const __half* __restrict__ h2h,
                                              const float* __restrict__ el2,
                                              const float* __restrict__ er2,
                                              const float* __restrict__ b2,
                                              float* __restrict__ out) {
    const int t = threadIdx.x, w = t >> 6, l = t & 63;
    const int n = blockIdx.x * 2 + w;
    const int beg = offs[n], deg = offs[n + 1] - beg;
    __shared__ int   lsrc[2][16];
    __shared__ float lw[2][16];
    __shared__ float pw[2][16];
    const int g = l & 7, es = l >> 3;
    const int e = l & 15;
    const float erd = er2[n];
    float m_run = -1e30f, z_run = 0.f;
    float acc[8];
    #pragma unroll
    for (int j = 0; j < 8; j++) acc[j] = 0.f;
    const float4* hp4 = (const float4*)h2h;

    for (int base = 0; base < deg; base += 16) {
        if (l < 16) {
            int2 pr = (base + l < deg) ? csr[beg + base + l] : make_int2(0, 0);
            lsrc[w][l] = pr.x;
            lw[w][l] = __int_as_float(pr.y);
        }
        asm volatile("" ::: "memory");
        float lg = -1e30f;
        if (base + e < deg) {
            const float v = el2[lsrc[w][e]] + erd;
            lg = v > 0.f ? v : 0.2f * v;
        }
        float tm = lg;
        tm = fmaxf(tm, __shfl_xor(tm, 1, 64));
        tm = fmaxf(tm, __shfl_xor(tm, 2, 64));
        tm = fmaxf(tm, __shfl_xor(tm, 4, 64));
        tm = fmaxf(tm, __shfl_xor(tm, 8, 64));
        const float m_new = fmaxf(m_run, tm);
        const float sc = __expf(m_run - m_new);
        const float p = __expf(lg - m_new);
        float za = p;
        za += __shfl_xor(za, 1, 64);
        za += __shfl_xor(za, 2, 64);
        za += __shfl_xor(za, 4, 64);
        za += __shfl_xor(za, 8, 64);
        z_run = z_run * sc + za;
        m_run = m_new;
        if (l < 16) pw[w][l] = p * lw[w][l];
        asm volatile("" ::: "memory");
        #pragma unroll
        for (int j = 0; j < 8; j++) acc[j] *= sc;
        const int sA = lsrc[w][es], sB = lsrc[w][es + 8];
        const float pA = pw[w][es], pB = pw[w][es + 8];
        const float4 vA = hp4[(size_t)sA * 8 + g];
        const float4 vB = hp4[(size_t)sB * 8 + g];
        #pragma unroll
        for (int q = 0; q < 4; q++) {
            const __half2 hA = ((const __half2*)&vA)[q];
            const __half2 hB = ((const __half2*)&vB)[q];
            const float2 fA = __half22float2(hA), fB = __half22float2(hB);
            acc[2 * q]     = fmaf(pA, fA.x, fmaf(pB, fB.x, acc[2 * q]));
            acc[2 * q + 1] = fmaf(pA, fA.y, fmaf(pB, fB.y, acc[2 * q + 1]));
        }
        asm volatile("" ::: "memory");
    }
    // reduce over es (bits 3,4,5)
    #pragma unroll
    for (int j = 0; j < 8; j++) {
        acc[j] += __shfl_xor(acc[j], 8, 64);
        acc[j] += __shfl_xor(acc[j], 16, 64);
        acc[j] += __shfl_xor(acc[j], 32, 64);
    }
    if (l < 8) {
        const float inv = (deg > 0) ? 1.f / z_run : 0.f;
        const float4* b4 = (const float4*)b2;
        const float4 bb0 = b4[g * 2], bb1 = b4[g * 2 + 1];
        float4 o0, o1;
        o0.x = acc[0] * inv + bb0.x;
        o0.y = acc[1] * inv + bb0.y;
        o0.z = acc[2] * inv + bb0.z;
        o0.w = acc[3] * inv + bb0.w;
        o1.x = acc[4] * inv + bb1.x;
        o1.y = acc[5] * inv + bb1.y;
        o1.z = acc[6] * inv + bb1.z;
        o1.w = acc[7] * inv + bb1.w;
        float4* op = (float4*)(out + (size_t)n * 64 + g * 8);
        op[0] = o0; op[1] = o1;
    }
}

// ---------------- host ----------------

extern "C" void kernel_launch(void* const* d_in, const int* in_sizes, int n_in,
                              void* d_out, int out_size, void* d_ws, size_t ws_size,
                              hipStream_t stream) {
    const float* feat = (const float*)d_in[0];
    const int*   srcv = (const int*)d_in[1];
    const int*   dstv = (const int*)d_in[2];
    const float* wE   = (const float*)d_in[3];
    const float* W1   = (const float*)d_in[4];
    const float* al1  = (const float*)d_in[5];
    const float* ar1  = (const float*)d_in[6];
    const float* b1   = (const float*)d_in[7];
    const float* W2   = (const float*)d_in[8];
    const float* al2  = (const float*)d_in[9];
    const float* ar2  = (const float*)d_in[10];
    const float* b2   = (const float*)d_in[11];
    float* out = (float*)d_out;

    char* ws = (char*)d_ws;
    size_t off = 0;
    auto take = [&](size_t bytes) -> char* {
        char* pp = ws + off;
        off = (off + bytes + 255) & ~(size_t)255;
        return pp;
    };
    __half* h1h = (__half*)take((size_t)NN * 128 * 2);
    __half* h2h = (__half*)take((size_t)NN * 64 * 2);
    float* h2in = (float*)take((size_t)NN * 128 * 4);
    float* el1  = (float*)take((size_t)NN * 8 * 4);
    float* er1  = (float*)take((size_t)NN * 8 * 4);
    float* el2  = (float*)take((size_t)NN * 4);
    float* er2  = (float*)take((size_t)NN * 4);
    int* counts = (int*)take((size_t)NN * 4);
    int* offs   = (int*)take((size_t)(NN + 1) * 4);
    int* cursors= (int*)take((size_t)NN * 4);
    int2* csr   = (int2*)take((size_t)NE * 8);
    int* bsum   = (int*)take((size_t)NB_C * 4);
    int* boff   = (int*)take((size_t)NB_C * 4);

    init_counts_k<<<NB_C, 256, 0, stream>>>(counts);
    hist_k<<<(NE + 255) / 256, 256, 0, stream>>>(dstv, counts);
    partial_k<<<NB_C, 256, 0, stream>>>(counts, bsum);
    scanb_k<<<1, 256, 0, stream>>>(bsum, boff, offs + NN);
    offs_k<<<NB_C, 256, 0, stream>>>(counts, boff, offs, cursors);
    scatter_k<<<(NE + 255) / 256, 256, 0, stream>>>(dstv, srcv, wE, cursors, csr);
    proj1_k<<<NN / 16, 64, 0, stream>>>(feat, W1, al1, ar1, h1h, el1, er1);
    agg1_k<<<NN / 2, 128, 0, stream>>>(offs, csr, h1h, el1, er1, b1, h2in);
    proj2_k<<<NN / 16, 64, 0, stream>>>(h2in, W2, al2, ar2, h2h, el2, er2);
    agg2_k<<<NN / 2, 128, 0, stream>>>(offs, csr, h2h, el2, er2, b2, out);
}